// Round 9
// baseline (638.537 us; speedup 1.0000x reference)
//
#include <hip/hip_runtime.h>
#include <stdint.h>

typedef float f2 __attribute__((ext_vector_type(2)));
typedef float f4 __attribute__((ext_vector_type(4)));
typedef _Float16 h2 __attribute__((ext_vector_type(2)));

// res[l] = floor(16 * b^l), b = exp((ln512 - ln16)/15) in fp32.
__constant__ float c_res[16] = {16.f, 20.f, 25.f, 32.f, 40.f, 50.f, 64.f, 80.f,
                                101.f, 128.f, 161.f, 203.f, 256.f, 322.f, 406.f, 512.f};

#define HASH_MASK ((1u << 19) - 1u)
#define P1 2654435761u
#define P2 805459861u
#define PTS_PER_THREAD 4

// Model (R0-R8): encode is per-CU miss-slot x latency bound (~430us for 16
// levels); transpose-class kernels sit at an empirical ~1.2 TB/s wall (~174us
// fp16). R7 proved (K1==K2==282us) that transpose blocks interleaved 1:4 into
// an encode dispatch ride FREE on the spare miss-slot capacity -- R7's
// regression was solely its NT tmp stores (+31% on the encode). R9 therefore =
// R8's plain fp16 tmp encode + R7's fusion: K1 encode L0-7, K2 encode L8-15
// with rows 0-7 transpose fused (every 5th group), K3 transpose rows 8-15.

__device__ __forceinline__ void encode_block(
    const float* __restrict__ x,
    const float* __restrict__ tables,
    h2* __restrict__ tmp,
    float* __restrict__ mask_out,
    int n_points, int level, int trow, int chunk)
{
    float res  = c_res[level];
    float grid = 1.0f / res;
    const f2* __restrict__ tab =
        (const f2*)tables + ((size_t)level << 19);   // 2^19 float2 per level
    const f4* __restrict__ tab4 = (const f4*)tab;    // 2^18 float4 per level

    int pbase = chunk * (256 * PTS_PER_THREAD) + threadIdx.x;

    uint32_t idx[PTS_PER_THREAD][8];
    float wx[PTS_PER_THREAD], wy[PTS_PER_THREAD], wz[PTS_PER_THREAD];
    bool valid[PTS_PER_THREAD];
    bool bxodd[PTS_PER_THREAD];
    int pp[PTS_PER_THREAD];

    #pragma unroll
    for (int s = 0; s < PTS_PER_THREAD; ++s) {
        int p = pbase + s * 256;
        pp[s] = p;
        valid[s] = (p < n_points);
        int pc = valid[s] ? p : 0;

        // Plain loads: x is re-read once per level (16x); let L2/L3 cache it.
        float x0 = x[3 * (size_t)pc + 0];
        float x1 = x[3 * (size_t)pc + 1];
        float x2 = x[3 * (size_t)pc + 2];

        if (level == 0 && valid[s]) {
            bool keep = (x0 >= 0.f) & (x0 <= 1.f) &
                        (x1 >= 0.f) & (x1 <= 1.f) &
                        (x2 >= 0.f) & (x2 <= 1.f);
            mask_out[pc] = keep ? 1.0f : 0.0f;
        }

        x0 = fminf(fmaxf(x0, 0.f), 1.f);
        x1 = fminf(fmaxf(x1, 0.f), 1.f);
        x2 = fminf(fmaxf(x2, 0.f), 1.f);

        // Keep the exact fp32 sequence of the verified kernel (floor(x/grid)),
        // grid = 1/res: changing to x*res can flip buckets by 1 ulp.
        float b0 = floorf(x0 / grid);
        float b1 = floorf(x1 / grid);
        float b2 = floorf(x2 / grid);

        wx[s] = (x0 - b0 * grid) / grid;
        wy[s] = (x1 - b1 * grid) / grid;
        wz[s] = (x2 - b2 * grid) / grid;

        uint32_t bx = (uint32_t)b0;
        uint32_t by = (uint32_t)b1;
        uint32_t bz = (uint32_t)b2;

        bxodd[s] = (bx & 1u) != 0u;

        uint32_t hx0 = bx;        uint32_t hx1 = bx + 1u;
        uint32_t hy0 = by * P1;   uint32_t hy1 = hy0 + P1;
        uint32_t hz0 = bz * P2;   uint32_t hz1 = hz0 + P2;

        idx[s][0] = (hx0 ^ hy0 ^ hz0) & HASH_MASK;
        idx[s][1] = (hx0 ^ hy0 ^ hz1) & HASH_MASK;
        idx[s][2] = (hx0 ^ hy1 ^ hz0) & HASH_MASK;
        idx[s][3] = (hx0 ^ hy1 ^ hz1) & HASH_MASK;
        idx[s][4] = (hx1 ^ hy0 ^ hz0) & HASH_MASK;
        idx[s][5] = (hx1 ^ hy0 ^ hz1) & HASH_MASK;
        idx[s][6] = (hx1 ^ hy1 ^ hz0) & HASH_MASK;
        idx[s][7] = (hx1 ^ hy1 ^ hz1) & HASH_MASK;
    }

    // Issue all gathers before any consumption. Even-bx lanes: 4x16B paired
    // loads (idx[j] and idx[j]^1 == idx[j+4] share a float4). Odd-bx: 8x8B.
    f2 e[PTS_PER_THREAD][8];
    #pragma unroll
    for (int s = 0; s < PTS_PER_THREAD; ++s) {
        if (!bxodd[s]) {
            #pragma unroll
            for (int j = 0; j < 4; ++j) {
                uint32_t q = idx[s][j];
                f4 v = tab4[q >> 1];
                f2 lov = {v.x, v.y};
                f2 hiv = {v.z, v.w};
                bool hi = (q & 1u) != 0u;
                e[s][j]     = hi ? hiv : lov;   // entry q     (x = bx)
                e[s][j + 4] = hi ? lov : hiv;   // entry q ^ 1 (x = bx+1)
            }
        } else {
            #pragma unroll
            for (int c = 0; c < 8; ++c)
                e[s][c] = tab[idx[s][c]];
        }
    }

    #pragma unroll
    for (int s = 0; s < PTS_PER_THREAD; ++s) {
        float owx = 1.f - wx[s], owy = 1.f - wy[s], owz = 1.f - wz[s];

        f2 c00 = e[s][0] * owx + e[s][4] * wx[s];
        f2 c01 = e[s][1] * owx + e[s][5] * wx[s];
        f2 c10 = e[s][2] * owx + e[s][6] * wx[s];
        f2 c11 = e[s][3] * owx + e[s][7] * wx[s];

        f2 c0 = c00 * owy + c10 * wy[s];
        f2 c1 = c01 * owy + c11 * wy[s];

        f2 cv = c0 * owz + c1 * wz[s];

        if (valid[s]) {
            // fp16x2: coalesced 4B/lane, full-line contiguous per wave,
            // PLAIN store -> L2-merged (NT here cost +31% in R7).
            h2 hv = {(_Float16)cv.x, (_Float16)cv.y};
            tmp[(size_t)trow * n_points + pp[s]] = hv;
        }
    }
}

// Fused kernel. Blocks in groups of 8 (r = blockIdx%8 keeps XCD pinning for
// encode). If tr_cnt > 0, every 5th group (g%5==4) is a transpose group,
// draining tmp rows [tr_row_base,+8) -> out while encode groups run: their
// ~20x-fewer misses ride the spare per-CU miss-slot capacity (R7: K2==K1).
__global__ __launch_bounds__(256, 4) void fused_kernel(
    const float* __restrict__ x,
    const float* __restrict__ tables,
    h2* __restrict__ tmp,
    float* __restrict__ out,
    float* __restrict__ mask_out,
    int n_points,
    int n_tiles,
    int tr_cnt,          // # transpose groups (0 = pure encode)
    int tr_row_base,     // tmp row base for transpose
    int tr_out_k,        // out4 slot base (levels base / 2)
    int enc_level_base,  // 0 or 8
    int enc_trow_base)   // tmp row base for encode writes
{
    int g = (int)blockIdx.x >> 3;
    int r = (int)blockIdx.x & 7;

    if (tr_cnt > 0 && (g % 5) == 4) {
        __shared__ h2 lds[8][258];
        int tid = (g / 5) * 8 + r;
        int trb = tr_cnt * 8;
        int t = threadIdx.x;
        f4* out4 = (f4*)out;
        for (int tile = tid; tile < n_tiles; tile += trb) {
            int p0 = tile * 256;
            #pragma unroll
            for (int l = 0; l < 8; ++l) {
                int p = p0 + t;
                lds[l][t] = tmp[(size_t)(tr_row_base + l) * n_points +
                                (p < n_points ? p : 0)];
            }
            __syncthreads();
            #pragma unroll
            for (int i = 0; i < 4; ++i) {
                int gi = i * 256 + t;
                int pidx = gi >> 2;
                int k = gi & 3;
                h2 a = lds[2 * k][pidx];
                h2 b = lds[2 * k + 1][pidx];
                int p = p0 + pidx;
                if (p < n_points) {
                    f4 w = {(float)a.x, (float)a.y, (float)b.x, (float)b.y};
                    out4[(size_t)p * 8 + tr_out_k + k] = w;
                }
            }
            __syncthreads();
        }
        return;
    }

    int gg = (tr_cnt > 0) ? (g - (g + 1) / 5) : g;   // encode group index
    encode_block(x, tables, tmp, mask_out, n_points,
                 r + enc_level_base, r + enc_trow_base, gg);
}

// Standalone LDS transpose (one block per 256-pt tile): tmp rows
// [row_base,+8) -> out4 slots [out_k, out_k+4).
__global__ __launch_bounds__(256) void transpose8_kernel(
    const h2* __restrict__ tmp,
    float* __restrict__ out,
    int n_points, int row_base, int out_k)
{
    __shared__ h2 lds[8][258];
    int t = threadIdx.x;
    int p0 = blockIdx.x * 256;

    #pragma unroll
    for (int l = 0; l < 8; ++l) {
        int p = p0 + t;
        lds[l][t] = tmp[(size_t)(row_base + l) * n_points +
                        (p < n_points ? p : 0)];
    }
    __syncthreads();

    f4* out4 = (f4*)out;
    #pragma unroll
    for (int i = 0; i < 4; ++i) {
        int gi = i * 256 + t;
        int pidx = gi >> 2;
        int k = gi & 3;
        h2 a = lds[2 * k][pidx];
        h2 b = lds[2 * k + 1][pidx];
        int p = p0 + pidx;
        if (p < n_points) {
            f4 w = {(float)a.x, (float)a.y, (float)b.x, (float)b.y};
            out4[(size_t)p * 8 + out_k + k] = w;
        }
    }
}

// Direct-write fallback (no workspace): R2-style single kernel.
__global__ __launch_bounds__(256, 4) void encode_direct_kernel(
    const float* __restrict__ x,
    const float* __restrict__ tables,
    float* __restrict__ out,
    float* __restrict__ mask_out,
    int n_points,
    int blocks_per_phase)
{
    int bid = blockIdx.x;
    int level_base = 0;
    if (bid >= blocks_per_phase) { bid -= blocks_per_phase; level_base = 8; }
    int level = (bid & 7) + level_base;
    int chunk = bid >> 3;

    // Inline minimal direct version (writes f2 straight into out).
    float res  = c_res[level];
    float grid = 1.0f / res;
    const f2* __restrict__ tab = (const f2*)tables + ((size_t)level << 19);

    int pbase = chunk * (256 * PTS_PER_THREAD) + threadIdx.x;
    #pragma unroll
    for (int s = 0; s < PTS_PER_THREAD; ++s) {
        int p = pbase + s * 256;
        bool valid = (p < n_points);
        int pc = valid ? p : 0;
        float x0 = x[3 * (size_t)pc + 0];
        float x1 = x[3 * (size_t)pc + 1];
        float x2 = x[3 * (size_t)pc + 2];
        if (level == 0 && valid) {
            bool keep = (x0 >= 0.f) & (x0 <= 1.f) & (x1 >= 0.f) &
                        (x1 <= 1.f) & (x2 >= 0.f) & (x2 <= 1.f);
            mask_out[pc] = keep ? 1.0f : 0.0f;
        }
        x0 = fminf(fmaxf(x0, 0.f), 1.f);
        x1 = fminf(fmaxf(x1, 0.f), 1.f);
        x2 = fminf(fmaxf(x2, 0.f), 1.f);
        float b0 = floorf(x0 / grid);
        float b1 = floorf(x1 / grid);
        float b2 = floorf(x2 / grid);
        float wx = (x0 - b0 * grid) / grid;
        float wy = (x1 - b1 * grid) / grid;
        float wz = (x2 - b2 * grid) / grid;
        uint32_t bx = (uint32_t)b0, by = (uint32_t)b1, bz = (uint32_t)b2;
        uint32_t hx0 = bx, hx1 = bx + 1u;
        uint32_t hy0 = by * P1, hy1 = hy0 + P1;
        uint32_t hz0 = bz * P2, hz1 = hz0 + P2;
        f2 e[8];
        e[0] = tab[(hx0 ^ hy0 ^ hz0) & HASH_MASK];
        e[1] = tab[(hx0 ^ hy0 ^ hz1) & HASH_MASK];
        e[2] = tab[(hx0 ^ hy1 ^ hz0) & HASH_MASK];
        e[3] = tab[(hx0 ^ hy1 ^ hz1) & HASH_MASK];
        e[4] = tab[(hx1 ^ hy0 ^ hz0) & HASH_MASK];
        e[5] = tab[(hx1 ^ hy0 ^ hz1) & HASH_MASK];
        e[6] = tab[(hx1 ^ hy1 ^ hz0) & HASH_MASK];
        e[7] = tab[(hx1 ^ hy1 ^ hz1) & HASH_MASK];
        float owx = 1.f - wx, owy = 1.f - wy, owz = 1.f - wz;
        f2 c00 = e[0] * owx + e[4] * wx;
        f2 c01 = e[1] * owx + e[5] * wx;
        f2 c10 = e[2] * owx + e[6] * wx;
        f2 c11 = e[3] * owx + e[7] * wx;
        f2 c0 = c00 * owy + c10 * wy;
        f2 c1 = c01 * owy + c11 * wy;
        f2 cv = c0 * owz + c1 * wz;
        if (valid) {
            f2* dst = (f2*)(out + (size_t)p * 32) + level;
            *dst = cv;
        }
    }
}

extern "C" void kernel_launch(void* const* d_in, const int* in_sizes, int n_in,
                              void* d_out, int out_size, void* d_ws, size_t ws_size,
                              hipStream_t stream) {
    const float* x      = (const float*)d_in[0];
    const float* tables = (const float*)d_in[1];
    float* out = (float*)d_out;
    int n_points = in_sizes[0] / 3;
    float* mask_out = out + (size_t)n_points * 32;

    int chunks = (n_points + 256 * PTS_PER_THREAD - 1) / (256 * PTS_PER_THREAD);
    int n_tiles = (n_points + 255) / 256;

    size_t need_full = (size_t)n_points * 16 * sizeof(h2);  // 64MB @ 1M pts
    size_t need_half = (size_t)n_points * 8 * sizeof(h2);   // 32MB

    if (n_points > 0 && ws_size >= need_full) {
        h2* tmp = (h2*)d_ws;
        // K1: encode levels 0-7 -> rows 0-7 (pure encode).
        hipLaunchKernelGGL(fused_kernel, dim3(chunks * 8), dim3(256), 0, stream,
                           x, tables, tmp, out, mask_out, n_points,
                           n_tiles, 0, 0, 0, /*enc_lvl=*/0, /*trow=*/0);
        // K2: encode levels 8-15 -> rows 8-15, + transpose rows 0-7 fused.
        int total = chunks + (chunks + 3) / 4;
        if (total < 5) total = 5;
        while (total - total / 5 < chunks) ++total;
        int tr_cnt = total / 5;
        hipLaunchKernelGGL(fused_kernel, dim3(total * 8), dim3(256), 0, stream,
                           x, tables, tmp, out, mask_out, n_points,
                           n_tiles, tr_cnt, /*row*/0, /*out_k*/0,
                           /*enc_lvl=*/8, /*trow=*/8);
        // K3: transpose rows 8-15 (exposed tail).
        hipLaunchKernelGGL(transpose8_kernel, dim3(n_tiles), dim3(256), 0,
                           stream, tmp, out, n_points, 8, 4);
    } else if (n_points > 0 && ws_size >= need_half) {
        h2* tmp = (h2*)d_ws;
        // Serial half mode: rows 0-7 reused per phase.
        hipLaunchKernelGGL(fused_kernel, dim3(chunks * 8), dim3(256), 0, stream,
                           x, tables, tmp, out, mask_out, n_points,
                           n_tiles, 0, 0, 0, 0, 0);
        hipLaunchKernelGGL(transpose8_kernel, dim3(n_tiles), dim3(256), 0,
                           stream, tmp, out, n_points, 0, 0);
        hipLaunchKernelGGL(fused_kernel, dim3(chunks * 8), dim3(256), 0, stream,
                           x, tables, tmp, out, mask_out, n_points,
                           n_tiles, 0, 0, 0, 8, 0);
        hipLaunchKernelGGL(transpose8_kernel, dim3(n_tiles), dim3(256), 0,
                           stream, tmp, out, n_points, 0, 4);
    } else {
        hipLaunchKernelGGL(encode_direct_kernel, dim3(chunks * 16), dim3(256),
                           0, stream, x, tables, out, mask_out, n_points,
                           chunks * 8);
    }
}

// Round 10
// 598.338 us; speedup vs baseline: 1.0672x; 1.0672x over previous
//
#include <hip/hip_runtime.h>
#include <stdint.h>

typedef float f2 __attribute__((ext_vector_type(2)));
typedef float f4 __attribute__((ext_vector_type(4)));
typedef _Float16 h2 __attribute__((ext_vector_type(2)));

// res[l] = floor(16 * b^l), b = exp((ln512 - ln16)/15) in fp32.
__constant__ float c_res[16] = {16.f, 20.f, 25.f, 32.f, 40.f, 50.f, 64.f, 80.f,
                                101.f, 128.f, 161.f, 203.f, 256.f, 322.f, 406.f, 512.f};

#define HASH_MASK ((1u << 19) - 1u)
#define P1 2654435761u
#define P2 805459861u
#define PTS_PER_THREAD 4

// Model (R0-R9): encode = per-CU miss-slot x latency bound; 96M paired
// requests x ~169cy / (64 slots x 256 CU x 2.4GHz) ~= 413us -> measured 430
// is ~96% of the structural floor. Fusion of transpose into encode is
// PERMANENTLY REJECTED: R7-K2 (339MB) and R9-K2 (316MB) both show the
// co-resident transpose evicting the XCD-pinned tables; R7's "free" result
// was an artifact of its NT-slowed encode.
// R10 single change vs R8 (604us best): the transpose's out stores become
// NONTEMPORAL. Rationale: plain stores write-allocate (RFO) ~132MB of out
// lines from HBM before overwriting them. R4's NT disaster was per-lane
// 128B-stride instructions (16B x 64 scattered lines -> MC RMW); R8's
// transpose store instructions are 1KB fully contiguous (16 complete 64B
// lines each), so NT can burst full lines: no RFO, no RMW, no L2/L3 churn.
template <bool WRITE_TMP>
__global__ __launch_bounds__(256, 4) void hash_encode_kernel(
    const float* __restrict__ x,
    const float* __restrict__ tables,
    h2* __restrict__ tmp,            // [nl][n_points] level-major, fp16x2
    float* __restrict__ out,         // only used when !WRITE_TMP
    float* __restrict__ mask_out,
    int n_points,
    int blocks_per_phase,
    int level_base_arg,              // used when !two_phase
    int two_phase)                   // 1: grid covers both phases
{
    int bid = blockIdx.x;
    int level_base = level_base_arg;
    if (two_phase) {
        level_base = 0;
        if (bid >= blocks_per_phase) { bid -= blocks_per_phase; level_base = 8; }
    }
    int level = (bid & 7) + level_base;
    // tmp row index: full mode stores all 16 levels; half mode stores 8.
    int trow = two_phase ? level : (bid & 7);
    int chunk = bid >> 3;

    float res  = c_res[level];
    float grid = 1.0f / res;
    const f2* __restrict__ tab =
        (const f2*)tables + ((size_t)level << 19);   // 2^19 float2 per level
    const f4* __restrict__ tab4 = (const f4*)tab;    // 2^18 float4 per level

    int pbase = chunk * (256 * PTS_PER_THREAD) + threadIdx.x;

    uint32_t idx[PTS_PER_THREAD][8];
    float wx[PTS_PER_THREAD], wy[PTS_PER_THREAD], wz[PTS_PER_THREAD];
    bool valid[PTS_PER_THREAD];
    bool bxodd[PTS_PER_THREAD];
    int pp[PTS_PER_THREAD];

    #pragma unroll
    for (int s = 0; s < PTS_PER_THREAD; ++s) {
        int p = pbase + s * 256;
        pp[s] = p;
        valid[s] = (p < n_points);
        int pc = valid[s] ? p : 0;

        // Plain loads: x is re-read once per level (16x); let L2/L3 cache it.
        float x0 = x[3 * (size_t)pc + 0];
        float x1 = x[3 * (size_t)pc + 1];
        float x2 = x[3 * (size_t)pc + 2];

        if (level == 0 && valid[s]) {
            bool keep = (x0 >= 0.f) & (x0 <= 1.f) &
                        (x1 >= 0.f) & (x1 <= 1.f) &
                        (x2 >= 0.f) & (x2 <= 1.f);
            mask_out[pc] = keep ? 1.0f : 0.0f;
        }

        x0 = fminf(fmaxf(x0, 0.f), 1.f);
        x1 = fminf(fmaxf(x1, 0.f), 1.f);
        x2 = fminf(fmaxf(x2, 0.f), 1.f);

        // Keep the exact fp32 sequence of the verified kernel (floor(x/grid)),
        // grid = 1/res: changing to x*res can flip buckets by 1 ulp.
        float b0 = floorf(x0 / grid);
        float b1 = floorf(x1 / grid);
        float b2 = floorf(x2 / grid);

        wx[s] = (x0 - b0 * grid) / grid;
        wy[s] = (x1 - b1 * grid) / grid;
        wz[s] = (x2 - b2 * grid) / grid;

        uint32_t bx = (uint32_t)b0;
        uint32_t by = (uint32_t)b1;
        uint32_t bz = (uint32_t)b2;

        bxodd[s] = (bx & 1u) != 0u;

        uint32_t hx0 = bx;        uint32_t hx1 = bx + 1u;
        uint32_t hy0 = by * P1;   uint32_t hy1 = hy0 + P1;
        uint32_t hz0 = bz * P2;   uint32_t hz1 = hz0 + P2;

        idx[s][0] = (hx0 ^ hy0 ^ hz0) & HASH_MASK;
        idx[s][1] = (hx0 ^ hy0 ^ hz1) & HASH_MASK;
        idx[s][2] = (hx0 ^ hy1 ^ hz0) & HASH_MASK;
        idx[s][3] = (hx0 ^ hy1 ^ hz1) & HASH_MASK;
        idx[s][4] = (hx1 ^ hy0 ^ hz0) & HASH_MASK;
        idx[s][5] = (hx1 ^ hy0 ^ hz1) & HASH_MASK;
        idx[s][6] = (hx1 ^ hy1 ^ hz0) & HASH_MASK;
        idx[s][7] = (hx1 ^ hy1 ^ hz1) & HASH_MASK;
    }

    // Issue all gathers before any consumption. Even-bx lanes: 4x16B paired
    // loads (idx[j] and idx[j]^1 == idx[j+4] share a float4). Odd-bx: 8x8B.
    f2 e[PTS_PER_THREAD][8];
    #pragma unroll
    for (int s = 0; s < PTS_PER_THREAD; ++s) {
        if (!bxodd[s]) {
            #pragma unroll
            for (int j = 0; j < 4; ++j) {
                uint32_t q = idx[s][j];
                f4 v = tab4[q >> 1];
                f2 lov = {v.x, v.y};
                f2 hiv = {v.z, v.w};
                bool hi = (q & 1u) != 0u;
                e[s][j]     = hi ? hiv : lov;   // entry q     (x = bx)
                e[s][j + 4] = hi ? lov : hiv;   // entry q ^ 1 (x = bx+1)
            }
        } else {
            #pragma unroll
            for (int c = 0; c < 8; ++c)
                e[s][c] = tab[idx[s][c]];
        }
    }

    #pragma unroll
    for (int s = 0; s < PTS_PER_THREAD; ++s) {
        float owx = 1.f - wx[s], owy = 1.f - wy[s], owz = 1.f - wz[s];

        f2 c00 = e[s][0] * owx + e[s][4] * wx[s];
        f2 c01 = e[s][1] * owx + e[s][5] * wx[s];
        f2 c10 = e[s][2] * owx + e[s][6] * wx[s];
        f2 c11 = e[s][3] * owx + e[s][7] * wx[s];

        f2 c0 = c00 * owy + c10 * wy[s];
        f2 c1 = c01 * owy + c11 * wy[s];

        f2 cv = c0 * owz + c1 * wz[s];

        if (valid[s]) {
            if constexpr (WRITE_TMP) {
                // fp16x2: coalesced 4B/lane, full-line contiguous per wave,
                // PLAIN store -> L2-merged (NT here cost +31% in R7: per-
                // instruction footprint is only 256B, needs L2 merging).
                h2 hv = {(_Float16)cv.x, (_Float16)cv.y};
                tmp[(size_t)trow * n_points + pp[s]] = hv;
            } else {
                f2* dst = (f2*)(out + (size_t)pp[s] * 32) + level;
                *dst = cv;
            }
        }
    }
}

// LDS-tiled transpose, fp16 in / fp32 out: tmp[l][p] (h2) -> out[p][...].
// Stage 1: coalesced 4B/lane row reads, conflict-free LDS writes.
// Stage 2: consecutive lanes write consecutive 16B -> each store instruction
// covers 1KB = 16 COMPLETE 64B lines -> NONTEMPORAL store bursts full lines
// straight to the MC: no write-allocate RFO fetch (~132MB saved), no L2/L3
// pollution. (NT is only safe at this granularity; see R4 for the failure
// mode when per-instruction footprint is partial-line.)
template <int NL>
__global__ __launch_bounds__(256) void transpose_kernel(
    const h2* __restrict__ tmp,
    float* __restrict__ out,
    int n_points,
    int lb)
{
    __shared__ h2 lds[NL][258];
    constexpr int FP = NL / 2;             // f4 per point in this phase
    int t = threadIdx.x;
    int p0 = blockIdx.x * 256;

    #pragma unroll
    for (int l = 0; l < NL; ++l) {
        int p = p0 + t;
        lds[l][t] = tmp[(size_t)l * n_points + (p < n_points ? p : 0)];
    }
    __syncthreads();

    f4* out4 = (f4*)out;
    #pragma unroll
    for (int i = 0; i < FP; ++i) {
        int g = i * 256 + t;
        int pidx = g / FP;                 // point within tile
        int k = g % FP;                    // f4 slot within point
        h2 a = lds[2 * k][pidx];
        h2 b = lds[2 * k + 1][pidx];
        f4 w = {(float)a.x, (float)a.y, (float)b.x, (float)b.y};
        int p = p0 + pidx;
        if (p < n_points)
            __builtin_nontemporal_store(w, &out4[(size_t)p * 8 + lb / 2 + k]);
    }
}

extern "C" void kernel_launch(void* const* d_in, const int* in_sizes, int n_in,
                              void* d_out, int out_size, void* d_ws, size_t ws_size,
                              hipStream_t stream) {
    const float* x      = (const float*)d_in[0];
    const float* tables = (const float*)d_in[1];
    float* out = (float*)d_out;
    int n_points = in_sizes[0] / 3;
    float* mask_out = out + (size_t)n_points * 32;

    int chunks = (n_points + 256 * PTS_PER_THREAD - 1) / (256 * PTS_PER_THREAD);
    int blocks_per_phase = chunks * 8;
    int tblocks = (n_points + 255) / 256;

    size_t need_full = (size_t)n_points * 16 * sizeof(h2);  // 64MB @ 1M pts
    size_t need_half = (size_t)n_points * 8 * sizeof(h2);   // 32MB

    if (n_points > 0 && ws_size >= need_full) {
        h2* tmp = (h2*)d_ws;
        hipLaunchKernelGGL((hash_encode_kernel<true>), dim3(blocks_per_phase * 2),
                           dim3(256), 0, stream,
                           x, tables, tmp, out, mask_out, n_points,
                           blocks_per_phase, 0, 1);
        hipLaunchKernelGGL((transpose_kernel<16>), dim3(tblocks), dim3(256), 0,
                           stream, tmp, out, n_points, 0);
    } else if (n_points > 0 && ws_size >= need_half) {
        h2* tmp = (h2*)d_ws;
        // Phase A: levels 0-7 -> tmp rows 0-7 -> out floats [0,16)
        hipLaunchKernelGGL((hash_encode_kernel<true>), dim3(blocks_per_phase),
                           dim3(256), 0, stream,
                           x, tables, tmp, out, mask_out, n_points,
                           blocks_per_phase, 0, 0);
        hipLaunchKernelGGL((transpose_kernel<8>), dim3(tblocks), dim3(256), 0,
                           stream, tmp, out, n_points, 0);
        // Phase B: levels 8-15 -> tmp rows 0-7 -> out floats [16,32)
        hipLaunchKernelGGL((hash_encode_kernel<true>), dim3(blocks_per_phase),
                           dim3(256), 0, stream,
                           x, tables, tmp, out, mask_out, n_points,
                           blocks_per_phase, 8, 0);
        hipLaunchKernelGGL((transpose_kernel<8>), dim3(tblocks), dim3(256), 0,
                           stream, tmp, out, n_points, 8);
    } else {
        hipLaunchKernelGGL((hash_encode_kernel<false>), dim3(blocks_per_phase * 2),
                           dim3(256), 0, stream,
                           x, tables, (h2*)nullptr, out, mask_out, n_points,
                           blocks_per_phase, 0, 1);
    }
}